// Round 10
// baseline (530.877 us; speedup 1.0000x reference)
//
#include <hip/hip_runtime.h>
#include <hip/hip_bf16.h>

typedef __hip_bfloat16 bf16;
typedef unsigned int uint;
typedef unsigned short ushort;
typedef __attribute__((ext_vector_type(8))) short short8;  // 8 x bf16 (4 VGPRs)
typedef __attribute__((ext_vector_type(4))) float floatx4;

#define N_NODES 100000
#define N_PAD   100096   // multiple of 128 for the MFMA row tiling
#define E_EDGES 800000
#define NBLK    98       // ceil(N_NODES / 1024)
#define NSLICE  8        // one dst-slice per XCD (blockIdx % 8 ~ XCD id)
#define SLICE_N 12512    // ceil(N_NODES / NSLICE)
#define SLICE_BLOCKS 512 // blocks per slice row

static __device__ __forceinline__ uint packbf(float a, float b) {
  bf16 x = __float2bfloat16(a), y = __float2bfloat16(b);
  ushort ux = *reinterpret_cast<ushort*>(&x);
  ushort uy = *reinterpret_cast<ushort*>(&y);
  return (uint)ux | ((uint)uy << 16);
}
static __device__ __forceinline__ float lo16(uint u) { return __uint_as_float(u << 16); }
static __device__ __forceinline__ float hi16(uint u) { return __uint_as_float(u & 0xffff0000u); }

// ---------------- CSR build (by destination), XCD-sliced ----------------
__global__ void hist_sliced_k(const int* __restrict__ dst0, const int* __restrict__ dst1,
                              int* dg0, int* dg1) {
  int slice = blockIdx.x & (NSLICE - 1);
  int blk = blockIdx.x >> 3;
  int lo = slice * SLICE_N, hi = lo + SLICE_N;
  for (int i = blk * 256 + threadIdx.x; i < E_EDGES; i += SLICE_BLOCKS * 256) {
    int d0 = dst0[i];
    if (d0 >= lo && d0 < hi) atomicAdd(&dg0[d0], 1);
    int d1 = dst1[i];
    if (d1 >= lo && d1 < hi) atomicAdd(&dg1[d1], 1);
  }
}

__global__ void scat_sliced_k(const int* __restrict__ src0, const int* __restrict__ dst0,
                              const int* __restrict__ src1, const int* __restrict__ dst1,
                              int* fi0, int* fi1, int* cs0, int* cs1) {
  int slice = blockIdx.x & (NSLICE - 1);
  int blk = blockIdx.x >> 3;
  int lo = slice * SLICE_N, hi = lo + SLICE_N;
  for (int i = blk * 256 + threadIdx.x; i < E_EDGES; i += SLICE_BLOCKS * 256) {
    int d0 = dst0[i];
    if (d0 >= lo && d0 < hi) { int p = atomicAdd(&fi0[d0], 1); cs0[p] = src0[i]; }
    int d1 = dst1[i];
    if (d1 >= lo && d1 < hi) { int p = atomicAdd(&fi1[d1], 1); cs1[p] = src1[i]; }
  }
}

__global__ void scan_blk_k(const int* __restrict__ deg0, const int* __restrict__ deg1,
                           int* rp0, int* rp1, int* bsum) {
  __shared__ int s[1024];
  int r = blockIdx.y;
  const int* deg = r ? deg1 : deg0;
  int* rp = r ? rp1 : rp0;
  int i = blockIdx.x * 1024 + threadIdx.x;
  int v = (i < N_NODES) ? deg[i] : 0;
  s[threadIdx.x] = v;
  __syncthreads();
  for (int off = 1; off < 1024; off <<= 1) {
    int t = (threadIdx.x >= off) ? s[threadIdx.x - off] : 0;
    __syncthreads();
    s[threadIdx.x] += t;
    __syncthreads();
  }
  if (i < N_NODES) rp[i] = s[threadIdx.x] - v;
  if (threadIdx.x == 1023) bsum[r * NBLK + blockIdx.x] = s[1023];
}

__global__ void scan_top_k(int* bsum, int* rp0, int* rp1) {
  __shared__ int s[128];
  int r = blockIdx.x;
  int v = (threadIdx.x < NBLK) ? bsum[r * NBLK + threadIdx.x] : 0;
  s[threadIdx.x] = v;
  __syncthreads();
  for (int off = 1; off < 128; off <<= 1) {
    int t = (threadIdx.x >= off) ? s[threadIdx.x - off] : 0;
    __syncthreads();
    s[threadIdx.x] += t;
    __syncthreads();
  }
  if (threadIdx.x < NBLK) bsum[r * NBLK + threadIdx.x] = s[threadIdx.x] - v;
  if (threadIdx.x == 127) (r ? rp1 : rp0)[N_NODES] = s[127];
}

__global__ void scan_add_k(const int* __restrict__ bsum,
                           int* rp0, int* rp1, int* fi0, int* fi1) {
  int r = blockIdx.y;
  int i = blockIdx.x * 1024 + threadIdx.x;
  if (i >= N_NODES) return;
  int* rp = r ? rp1 : rp0;
  int* fi = r ? fi1 : fi0;
  int val = rp[i] + bsum[r * NBLK + blockIdx.x];
  rp[i] = val;
  fi[i] = val;
}

// ---------------- layer-2 transform, both relations via blockIdx.z ----------------
// Weight conversion fp32->bf16 is done inline in the LDS fill (wprep folded in).
__global__ __launch_bounds__(256) void mfma_t_k(const bf16* __restrict__ HB,
                                                const float* __restrict__ Wlb,
                                                const float* __restrict__ Wrb,
                                                const float* __restrict__ blb,
                                                const float* __restrict__ brb,
                                                bf16* __restrict__ XL0,
                                                bf16* __restrict__ XR0,
                                                bf16* __restrict__ XL1,
                                                bf16* __restrict__ XR1) {
  __shared__ short sW[256 * 72];
  int rel = blockIdx.z;
  const float* bl = blb + rel * 128;
  const float* br = brb + rel * 128;
  bf16* XLp = rel ? XL1 : XL0;
  bf16* XRp = rel ? XR1 : XR0;
  int t = threadIdx.x;
  // fill sW[c=t][k=0..63] from W[k][c] fp32 (coalesced reads, pairwise b32 writes)
  {
    const float* Wc = (t < 128) ? (Wlb + rel * 8192 + t) : (Wrb + rel * 8192 + t - 128);
#pragma unroll
    for (int i = 0; i < 32; ++i) {
      float a = Wc[(2 * i) * 128];
      float b = Wc[(2 * i + 1) * 128];
      *(uint*)(&sW[t * 72 + 2 * i]) = packbf(a, b);
    }
  }
  __syncthreads();
  int wave = t >> 6, lane = t & 63;
  int q = lane >> 4, m = lane & 15;
  int rowbase = blockIdx.x * 128 + wave * 32;
  short8 afr[2][2];
#pragma unroll
  for (int rt = 0; rt < 2; ++rt)
#pragma unroll
    for (int kh = 0; kh < 2; ++kh) {
      size_t row = (size_t)(rowbase + rt * 16 + m);
      afr[rt][kh] = *(const short8*)((const short*)HB + row * 64 + kh * 32 + q * 8);
    }
  for (int ct = 0; ct < 16; ++ct) {
    int col = ct * 16 + m;
    short8 b0 = *(const short8*)(&sW[col * 72 + q * 8]);
    short8 b1 = *(const short8*)(&sW[col * 72 + 32 + q * 8]);
    float bias = (col < 128) ? bl[col] : br[col - 128];
    bf16* X = (col < 128) ? XLp : XRp;
    int c128 = col & 127;
#pragma unroll
    for (int rt = 0; rt < 2; ++rt) {
      floatx4 acc = {0.f, 0.f, 0.f, 0.f};
      acc = __builtin_amdgcn_mfma_f32_16x16x32_bf16(afr[rt][0], b0, acc, 0, 0, 0);
      acc = __builtin_amdgcn_mfma_f32_16x16x32_bf16(afr[rt][1], b1, acc, 0, 0, 0);
      int r0 = rowbase + rt * 16 + q * 4;
#pragma unroll
      for (int i2 = 0; i2 < 4; ++i2) {
        int row = r0 + i2;
        if (row < N_NODES)
          X[(size_t)row * 128 + c128] = __float2bfloat16(acc[i2] + bias);
      }
    }
  }
}

// ---------------- layer-1 agg via rank-2 trick, BOTH relations (blockIdx.y) ----------------
// Writes per-relation fp32 partials (incl. per-relation bias, head-meaned).
// rel0 -> P0 (= d_out), rel1 -> P1 (aliases the XL1 region; mfma_t runs later).
__global__ __launch_bounds__(256) void aggl1f_k(
    const int* __restrict__ rp0, const int* __restrict__ cs0,
    const int* __restrict__ rp1, const int* __restrict__ cs1,
    const float* __restrict__ x,
    const float* __restrict__ Wlb, const float* __restrict__ blb,
    const float* __restrict__ Wrb, const float* __restrict__ brb,
    const float* __restrict__ attb, const float* __restrict__ biasb,
    float* __restrict__ P0, float* __restrict__ P1) {
  int rel = blockIdx.y;
  const int* rp = rel ? rp1 : rp0;
  const int* cs = rel ? cs1 : cs0;
  const float* Wl = Wlb + rel * 256;
  const float* blp = blb + rel * 128;
  const float* Wr = Wrb + rel * 256;
  const float* brp = brb + rel * 128;
  const float* att = attb + rel * 128;
  const float* bias = biasb + rel * 64;
  float* P = rel ? P1 : P0;

  int d = (blockIdx.x * 256 + threadIdx.x) >> 6;
  int lane = threadIdx.x & 63;
  if (d >= N_NODES) return;
  int half = lane >> 5;
  int l = lane & 31;
  int c0 = 4 * l;
  float4 w0 = *(const float4*)(Wl + c0);
  float4 w1 = *(const float4*)(Wl + 128 + c0);
  float4 v0 = *(const float4*)(Wr + c0);
  float4 v1 = *(const float4*)(Wr + 128 + c0);
  float4 bb = *(const float4*)(blp + c0);
  float4 rb = *(const float4*)(brp + c0);
  float4 aa = *(const float4*)(att + c0);
  float2 xd = *(const float2*)(x + 2 * d);
  float q0 = bb.x + rb.x + xd.x * v0.x + xd.y * v1.x;
  float q1 = bb.y + rb.y + xd.x * v0.y + xd.y * v1.y;
  float q2 = bb.z + rb.z + xd.x * v0.z + xd.y * v1.z;
  float q3 = bb.w + rb.w + xd.x * v0.w + xd.y * v1.w;
  float A0 = 0.f, A1 = 0.f, den = 0.f;
  int beg = rp[d], end = rp[d + 1];
  int j = beg + half;

#define L1_EDGE(XS)                                                          \
  {                                                                          \
    float e0 = q0 + XS.x * w0.x + XS.y * w1.x; e0 = fmaxf(e0, 0.2f * e0);    \
    float e1 = q1 + XS.x * w0.y + XS.y * w1.y; e1 = fmaxf(e1, 0.2f * e1);    \
    float e2 = q2 + XS.x * w0.z + XS.y * w1.z; e2 = fmaxf(e2, 0.2f * e2);    \
    float e3 = q3 + XS.x * w0.w + XS.y * w1.w; e3 = fmaxf(e3, 0.2f * e3);    \
    float p = e0 * aa.x + e1 * aa.y + e2 * aa.z + e3 * aa.w;                 \
    p += __shfl_xor(p, 1);                                                   \
    p += __shfl_xor(p, 2);                                                   \
    p += __shfl_xor(p, 4);                                                   \
    p += __shfl_xor(p, 8);                                                   \
    float ex = __expf(p);                                                    \
    den += ex; A0 += ex * XS.x; A1 += ex * XS.y;                             \
  }

  for (; j + 2 < end; j += 4) {
    int sA = cs[j], sB = cs[j + 2];
    float2 xA = *(const float2*)(x + 2 * sA);
    float2 xB = *(const float2*)(x + 2 * sB);
    L1_EDGE(xA);
    L1_EDGE(xB);
  }
  for (; j < end; j += 2) {
    int sA = cs[j];
    float2 xA = *(const float2*)(x + 2 * sA);
    L1_EDGE(xA);
  }
#undef L1_EDGE
  den += __shfl_xor(den, 32);
  A0 += __shfl_xor(A0, 32);
  A1 += __shfl_xor(A1, 32);
  float inv = 1.f / (den + 1e-16f);
  float S = den * inv;          // SUM(alpha): 1 normally, 0 for empty dst
  float a0 = A0 * inv, a1 = A1 * inv;
  float o0 = a0 * w0.x + a1 * w1.x + S * bb.x;
  float o1 = a0 * w0.y + a1 * w1.y + S * bb.y;
  float o2 = a0 * w0.z + a1 * w1.z + S * bb.z;
  float o3 = a0 * w0.w + a1 * w1.w + S * bb.w;
  o0 = 0.5f * (o0 + __shfl_xor(o0, 16));
  o1 = 0.5f * (o1 + __shfl_xor(o1, 16));
  o2 = 0.5f * (o2 + __shfl_xor(o2, 16));
  o3 = 0.5f * (o3 + __shfl_xor(o3, 16));
  if (lane >= 16) return;
  int cc = 4 * lane;
  o0 += bias[cc]; o1 += bias[cc + 1]; o2 += bias[cc + 2]; o3 += bias[cc + 3];
  size_t oi = (size_t)d * 64 + cc;
  *(float4*)(P + oi) = make_float4(o0, o1, o2, o3);
}

// ---------------- layer-1 finalize: 0.5*(P0+P1), relu, bf16-pack -> HB ----------------
__global__ void fin1_k(const float* __restrict__ P0, const float* __restrict__ P1,
                       uint* __restrict__ HB) {
  int tid = blockIdx.x * 256 + threadIdx.x;   // N*32 threads, 2 channels each
  if (tid >= N_NODES * 32) return;
  float2 a = *(const float2*)(P0 + 2 * (size_t)tid);
  float2 b = *(const float2*)(P1 + 2 * (size_t)tid);
  float v0 = fmaxf(0.5f * (a.x + b.x), 0.f);
  float v1 = fmaxf(0.5f * (a.y + b.y), 0.f);
  HB[tid] = packbf(v0, v1);
}

// ---------------- layer-2 agg (r6-proven): 32 lanes/edge, uint2, scalar f32 ----------------
struct EdgeAcc { float a0, a1, a2, a3, den; };

static __device__ __forceinline__ void edge_step(
    uint2 u, float xr0, float xr1, float xr2, float xr3,
    float at0, float at1, float at2, float at3, EdgeAcc& A) {
  float x0 = lo16(u.x), x1 = hi16(u.x), x2 = lo16(u.y), x3 = hi16(u.y);
  float e0 = x0 + xr0; e0 = e0 > 0.f ? e0 : 0.2f * e0;
  float e1 = x1 + xr1; e1 = e1 > 0.f ? e1 : 0.2f * e1;
  float e2 = x2 + xr2; e2 = e2 > 0.f ? e2 : 0.2f * e2;
  float e3 = x3 + xr3; e3 = e3 > 0.f ? e3 : 0.2f * e3;
  float p = e0 * at0 + e1 * at1 + e2 * at2 + e3 * at3;
  p += __shfl_xor(p, 1);
  p += __shfl_xor(p, 2);
  p += __shfl_xor(p, 4);
  p += __shfl_xor(p, 8);        // 16-lane head-group total
  float ex = __expf(p);
  A.den += ex;
  A.a0 += ex * x0; A.a1 += ex * x1; A.a2 += ex * x2; A.a3 += ex * x3;
}

__global__ __launch_bounds__(256) void aggh_k(
    const int* __restrict__ rp, const int* __restrict__ cs,
    const bf16* __restrict__ XL, const bf16* __restrict__ XR,
    const float* __restrict__ att, const float* __restrict__ bias,
    float* __restrict__ accum, float* __restrict__ outf, int phase) {
  int d = (blockIdx.x * 256 + threadIdx.x) >> 6;
  int lane = threadIdx.x & 63;
  if (d >= N_NODES) return;
  int half = lane >> 5;
  int l = lane & 31;
  const float* at = att + 4 * l;
  float at0 = at[0], at1 = at[1], at2 = at[2], at3 = at[3];
  uint2 ur = *(const uint2*)(XR + (size_t)d * 128 + 4 * l);
  float xr0 = lo16(ur.x), xr1 = hi16(ur.x), xr2 = lo16(ur.y), xr3 = hi16(ur.y);
  EdgeAcc A = {0.f, 0.f, 0.f, 0.f, 0.f};
  int beg = rp[d], end = rp[d + 1];
  int j = beg + half;
  for (; j + 2 < end; j += 4) {
    int sA = cs[j], sB = cs[j + 2];
    uint2 uA = *(const uint2*)(XL + (size_t)sA * 128 + 4 * l);
    uint2 uB = *(const uint2*)(XL + (size_t)sB * 128 + 4 * l);
    edge_step(uA, xr0, xr1, xr2, xr3, at0, at1, at2, at3, A);
    edge_step(uB, xr0, xr1, xr2, xr3, at0, at1, at2, at3, A);
  }
  for (; j < end; j += 2) {
    int s = cs[j];
    uint2 u = *(const uint2*)(XL + (size_t)s * 128 + 4 * l);
    edge_step(u, xr0, xr1, xr2, xr3, at0, at1, at2, at3, A);
  }
  A.den += __shfl_xor(A.den, 32);
  A.a0 += __shfl_xor(A.a0, 32);
  A.a1 += __shfl_xor(A.a1, 32);
  A.a2 += __shfl_xor(A.a2, 32);
  A.a3 += __shfl_xor(A.a3, 32);
  float inv = 1.f / (A.den + 1e-16f);
  A.a0 *= inv; A.a1 *= inv; A.a2 *= inv; A.a3 *= inv;
  float o0 = 0.5f * (A.a0 + __shfl_xor(A.a0, 16));
  float o1 = 0.5f * (A.a1 + __shfl_xor(A.a1, 16));
  float o2 = 0.5f * (A.a2 + __shfl_xor(A.a2, 16));
  float o3 = 0.5f * (A.a3 + __shfl_xor(A.a3, 16));
  if (lane >= 16) return;
  int c0 = 4 * lane;
  o0 += bias[c0]; o1 += bias[c0 + 1]; o2 += bias[c0 + 2]; o3 += bias[c0 + 3];
  size_t oi = (size_t)d * 64 + c0;
  if (phase == 0) {
    *(float4*)(accum + oi) = make_float4(o0, o1, o2, o3);
  } else {
    float4 pa = *(const float4*)(accum + oi);
    float v0 = 0.5f * (pa.x + o0);
    float v1 = 0.5f * (pa.y + o1);
    float v2 = 0.5f * (pa.z + o2);
    float v3 = 0.5f * (pa.w + o3);
    *(float4*)(outf + oi) = make_float4(v0, v1, v2, v3);
  }
}

extern "C" void kernel_launch(void* const* d_in, const int* in_sizes, int n_in,
                              void* d_out, int out_size, void* d_ws, size_t ws_size,
                              hipStream_t stream) {
  const float* x       = (const float*)d_in[0];
  const int*   e_adj   = (const int*)d_in[1];
  const int*   e_ray   = (const int*)d_in[2];
  const float* l1_Wl   = (const float*)d_in[3];
  const float* l1_bl   = (const float*)d_in[4];
  const float* l1_Wr   = (const float*)d_in[5];
  const float* l1_br   = (const float*)d_in[6];
  const float* l1_att  = (const float*)d_in[7];
  const float* l1_bias = (const float*)d_in[8];
  const float* l2_Wl   = (const float*)d_in[9];
  const float* l2_bl   = (const float*)d_in[10];
  const float* l2_Wr   = (const float*)d_in[11];
  const float* l2_br   = (const float*)d_in[12];
  const float* l2_att  = (const float*)d_in[13];
  const float* l2_bias = (const float*)d_in[14];
  float* out = (float*)d_out;

  char* w = (char*)d_ws;
  size_t off = 0;
  auto alloc = [&](size_t bytes) -> char* {
    char* p = w + off;
    off += (bytes + 255) & ~(size_t)255;
    return p;
  };
  bf16* XL0  = (bf16*)alloc((size_t)N_PAD * 128 * 2);   // layer-2 transforms
  bf16* XR0  = (bf16*)alloc((size_t)N_PAD * 128 * 2);
  bf16* XL1  = (bf16*)alloc((size_t)N_PAD * 128 * 2);   // ALSO aliases layer-1 P1
  bf16* XR1  = (bf16*)alloc((size_t)N_PAD * 128 * 2);
  bf16* HB   = (bf16*)alloc((size_t)N_PAD * 64 * 2);
  int* RP0   = (int*)alloc((size_t)(N_NODES + 1) * 4);
  int* RP1   = (int*)alloc((size_t)(N_NODES + 1) * 4);
  int* FI0   = (int*)alloc((size_t)N_NODES * 4);
  int* FI1   = (int*)alloc((size_t)N_NODES * 4);
  int* CS0   = (int*)alloc((size_t)E_EDGES * 4);
  int* CS1   = (int*)alloc((size_t)E_EDGES * 4);
  int* DG0   = (int*)alloc((size_t)N_NODES * 4);
  int* DG1   = (int*)alloc((size_t)N_NODES * 4);
  int* BSUM  = (int*)alloc(2 * NBLK * 4);
  float* ACC = out;             // layer-1 rel-0 partial AND layer-2 rel-0 partial
  float* P1  = (float*)XL1;     // layer-1 rel-1 partial (N*64 f32 = 25.6 MB fits);
                                // mfma_t overwrites XL1 AFTER fin1 consumed it.

  const int* src_adj = e_adj;
  const int* dst_adj = e_adj + E_EDGES;
  const int* src_ray = e_ray;
  const int* dst_ray = e_ray + E_EDGES;

  const int WNB = (N_NODES * 64) / 256;    // 25000 (one wave per node)
  const int MB  = N_PAD / 128;             // 782
  const int SB  = SLICE_BLOCKS * NSLICE;   // 4096
  const int FB  = (N_NODES * 32 + 255) / 256;  // 12500

  // CSR build
  size_t dgspan = (size_t)((char*)DG1 - (char*)DG0) + (size_t)N_NODES * 4;
  hipMemsetAsync(DG0, 0, dgspan, stream);
  hist_sliced_k<<<SB, 256, 0, stream>>>(dst_adj, dst_ray, DG0, DG1);
  scan_blk_k<<<dim3(NBLK, 2), 1024, 0, stream>>>(DG0, DG1, RP0, RP1, BSUM);
  scan_top_k<<<2, 128, 0, stream>>>(BSUM, RP0, RP1);
  scan_add_k<<<dim3(NBLK, 2), 1024, 0, stream>>>(BSUM, RP0, RP1, FI0, FI1);
  scat_sliced_k<<<SB, 256, 0, stream>>>(src_adj, dst_adj, src_ray, dst_ray,
                                        FI0, FI1, CS0, CS1);

  // ---- layer 1 (rank-2 trick): both relations concurrently, then finalize ----
  aggl1f_k<<<dim3(WNB, 2), 256, 0, stream>>>(RP0, CS0, RP1, CS1, x,
                                             l1_Wl, l1_bl, l1_Wr, l1_br,
                                             l1_att, l1_bias, ACC, P1);
  fin1_k<<<FB, 256, 0, stream>>>(ACC, P1, (uint*)HB);

  // ---- layer 2 (K=64): one MFMA dispatch (inline weight conv), per-relation agg ----
  mfma_t_k<<<dim3(MB, 1, 2), 256, 0, stream>>>(HB, l2_Wl, l2_Wr, l2_bl, l2_br,
                                               XL0, XR0, XL1, XR1);
  aggh_k<<<WNB, 256, 0, stream>>>(RP0, CS0, XL0, XR0, l2_att, l2_bias,
                                  ACC, nullptr, 0);
  aggh_k<<<WNB, 256, 0, stream>>>(RP1, CS1, XL1, XR1, l2_att + 128, l2_bias + 64,
                                  ACC, out, 1);
}